// Round 7
// baseline (142.073 us; speedup 1.0000x reference)
//
#include <hip/hip_runtime.h>

#define B_N 16
#define S_LEN 2048
#define D_DIM 128
#define NTH 32            // tiles per key-half (2 groups x 32 x 32 keys = 2048)

typedef __attribute__((ext_vector_type(16))) float f32x16;
typedef __attribute__((ext_vector_type(8)))  short short8;
typedef __attribute__((ext_vector_type(4)))  int   i32x4;

static __device__ __forceinline__ unsigned short f2bf(float f) {
  unsigned u = __builtin_bit_cast(unsigned, f);
  return (unsigned short)((u + 0x7fffu + ((u >> 16) & 1u)) >> 16);  // RNE
}

// ---------------- prepass: K,V -> bf16 in MFMA-frag-major layout ----------------
// Kf[(b*64+T)*8 + ks][lane][8]  = K[b][T*32 + (lane&31)][ks*16 + (lane>>5)*8 + j]
// Vf[(b*64+T)*8 + f ][lane][8]  = V[b][T*32 + (f>>2)*16 + (lane>>5)*8 + j][(f&3)*32 + (lane&31)]
// -> each frag is a contiguous, lane-indexed 1KB block: one coalesced dwordx4 per wave.
__global__ __launch_bounds__(256)
void prep_kernel(const float* __restrict__ K, const float* __restrict__ V,
                 unsigned short* __restrict__ Kf, unsigned short* __restrict__ Vf) {
  __shared__ unsigned short lds[32 * 132];
  const int bx = blockIdx.x;          // 1024 = 16 b x 64 T
  const int b  = bx >> 6;
  const int T  = bx & 63;
  const int t  = threadIdx.x;

  const float* Kb = K + ((size_t)b * S_LEN + T * 32) * D_DIM;
  const float* Vb = V + ((size_t)b * S_LEN + T * 32) * D_DIM;
  unsigned short* Kfb = Kf + ((size_t)(b * 64 + T) * 8) * 512;
  unsigned short* Vfb = Vf + ((size_t)(b * 64 + T) * 8) * 512;

  // ---- K frags: unit u = (ks = u>>6, lane = u&63), 2 units/thread ----
#pragma unroll
  for (int rep = 0; rep < 2; ++rep) {
    int u    = rep * 256 + t;
    int ks   = u >> 6;
    int lane = u & 63;
    const float* src = Kb + (size_t)(lane & 31) * D_DIM + ks * 16 + (lane >> 5) * 8;
    float4 a0 = *(const float4*)(src);
    float4 a1 = *(const float4*)(src + 4);
    unsigned w0 = (unsigned)f2bf(a0.x) | ((unsigned)f2bf(a0.y) << 16);
    unsigned w1 = (unsigned)f2bf(a0.z) | ((unsigned)f2bf(a0.w) << 16);
    unsigned w2 = (unsigned)f2bf(a1.x) | ((unsigned)f2bf(a1.y) << 16);
    unsigned w3 = (unsigned)f2bf(a1.z) | ((unsigned)f2bf(a1.w) << 16);
    *(uint4*)(Kfb + (size_t)ks * 512 + lane * 8) = make_uint4(w0, w1, w2, w3);
  }

  // ---- V tile -> LDS bf16 [32][132] (padded) ----
#pragma unroll
  for (int rep = 0; rep < 2; ++rep) {
    int id  = rep * 256 + t;          // 512 units of 8 floats
    int row = id >> 4;
    int c8  = (id & 15) * 8;
    float4 a0 = *(const float4*)(Vb + (size_t)row * D_DIM + c8);
    float4 a1 = *(const float4*)(Vb + (size_t)row * D_DIM + c8 + 4);
    unsigned short* d = &lds[row * 132 + c8];
    d[0] = f2bf(a0.x); d[1] = f2bf(a0.y); d[2] = f2bf(a0.z); d[3] = f2bf(a0.w);
    d[4] = f2bf(a1.x); d[5] = f2bf(a1.y); d[6] = f2bf(a1.z); d[7] = f2bf(a1.w);
  }
  __syncthreads();

  // ---- V frags out: unit u = (f = u>>6, lane = u&63) ----
#pragma unroll
  for (int rep = 0; rep < 2; ++rep) {
    int u    = rep * 256 + t;
    int f    = u >> 6;
    int lane = u & 63;
    int ks2  = f >> 2;
    int dt   = f & 3;
    int col  = dt * 32 + (lane & 31);
    int rbase = ks2 * 16 + (lane >> 5) * 8;
    unsigned w[4];
#pragma unroll
    for (int jj = 0; jj < 4; ++jj) {
      unsigned short e0 = lds[(rbase + 2 * jj) * 132 + col];
      unsigned short e1 = lds[(rbase + 2 * jj + 1) * 132 + col];
      w[jj] = (unsigned)e0 | ((unsigned)e1 << 16);
    }
    *(uint4*)(Vfb + (size_t)f * 512 + lane * 8) = make_uint4(w[0], w[1], w[2], w[3]);
  }
}

// ---------------- main attention: 128 thr x 1024 blocks, NO LDS / NO barriers in loop ----
// Each wave: 32 q-rows x one key-half (split-K pair {g0,g1} shares the block for the merge).
// K/V frags loaded straight from L2 (frag-major layout) into registers; compiler inserts
// counted vmcnt; waves free-run -> VALU/MFMA/VMEM overlap across the 8 desynced waves/CU.
__global__ __launch_bounds__(128, 2)
void attn_kernel(const float* __restrict__ Q, const unsigned short* __restrict__ Kf,
                 const unsigned short* __restrict__ Vf, float* __restrict__ O) {
  __shared__ __align__(16) float smem[4160];   // 16KB mo + ml1[32] + ml0[32]

  const int tid  = threadIdx.x;
  const int g    = tid >> 6;            // key-half group (wave 0 / wave 1)
  const int lane = tid & 63;
  const int l32  = lane & 31;
  const int half = lane >> 5;

  // XCD swizzle: all 64 q-blocks of one batch land on the same XCD (Kf/Vf L2 residency)
  const int i     = blockIdx.x;
  const int b     = (i & 7) * 2 + ((i >> 3) & 1);
  const int qt    = i >> 4;             // 0..63
  const int qbase = qt * 32;

  const float* Qb = Q + (size_t)b * S_LEN * D_DIM;
  // frag base for this (b, group): tiles T = g*32 + t
  const unsigned short* Kfb = Kf + ((size_t)(b * 64 + g * 32) * 8) * 512 + lane * 8;
  const unsigned short* Vfb = Vf + ((size_t)(b * 64 + g * 32) * 8) * 512 + lane * 8;

  // ---- Q B-frags (32x32x16: B[n=l32][k=half*8+j+16ks]), fp32->bf16 once ----
  short8 qa[8];
  {
    const float* qp = Qb + (size_t)(qbase + l32) * D_DIM + half * 8;
#pragma unroll
    for (int ks = 0; ks < 8; ++ks) {
      float4 a0 = *(const float4*)(qp + ks * 16);
      float4 a1 = *(const float4*)(qp + ks * 16 + 4);
      short8 f;
      f[0] = (short)f2bf(a0.x); f[1] = (short)f2bf(a0.y);
      f[2] = (short)f2bf(a0.z); f[3] = (short)f2bf(a0.w);
      f[4] = (short)f2bf(a1.x); f[5] = (short)f2bf(a1.y);
      f[6] = (short)f2bf(a1.z); f[7] = (short)f2bf(a1.w);
      qa[ks] = f;
    }
  }

  const f32x16 zf16 = {0.f,0.f,0.f,0.f,0.f,0.f,0.f,0.f,0.f,0.f,0.f,0.f,0.f,0.f,0.f,0.f};
  f32x16 oacc[4];
  float lsum = 0.f;
#pragma unroll
  for (int dt = 0; dt < 4; ++dt) oacc[dt] = zf16;

  const float SC = 0.08838834764831845f * 1.4426950408889634f; // 1/sqrt(128)*log2(e)

#define LOAD_K(dst, tt)                                                            \
  _Pragma("unroll")                                                                \
  for (int ks = 0; ks < 8; ++ks)                                                   \
    dst[ks] = *(const short8*)(Kfb + (((size_t)(tt) * 8 + ks) << 9));
#define LOAD_V(dst, tt)                                                            \
  _Pragma("unroll")                                                                \
  for (int f = 0; f < 8; ++f)                                                      \
    dst[f] = *(const short8*)(Vfb + (((size_t)(tt) * 8 + f) << 9));
#define QK(kreg, saccv)                                                            \
  _Pragma("unroll")                                                                \
  for (int ks = 0; ks < 8; ++ks)                                                   \
    saccv = __builtin_amdgcn_mfma_f32_32x32x16_bf16(kreg[ks], qa[ks], saccv, 0, 0, 0);
#define SOFTMAX(saccv, pf0v, pf1v)                                                 \
  {                                                                                \
    float p_[16];                                                                  \
    _Pragma("unroll")                                                              \
    for (int reg = 0; reg < 16; ++reg) {                                           \
      p_[reg] = exp2f(saccv[reg] * SC);                                            \
      lsum += p_[reg];                                                             \
    }                                                                              \
    int dw_[8];                                                                    \
    _Pragma("unroll")                                                              \
    for (int i2 = 0; i2 < 8; ++i2)                                                 \
      asm("v_cvt_pk_bf16_f32 %0, %1, %2"                                           \
          : "=v"(dw_[i2]) : "v"(p_[2 * i2]), "v"(p_[2 * i2 + 1]));                 \
    asm("v_permlane32_swap_b32 %0, %1" : "+v"(dw_[0]), "+v"(dw_[2]));              \
    asm("v_permlane32_swap_b32 %0, %1" : "+v"(dw_[1]), "+v"(dw_[3]));              \
    asm("v_permlane32_swap_b32 %0, %1" : "+v"(dw_[4]), "+v"(dw_[6]));              \
    asm("v_permlane32_swap_b32 %0, %1" : "+v"(dw_[5]), "+v"(dw_[7]));              \
    i32x4 f0_ = {dw_[0], dw_[1], dw_[2], dw_[3]};                                  \
    i32x4 f1_ = {dw_[4], dw_[5], dw_[6], dw_[7]};                                  \
    pf0v = __builtin_bit_cast(short8, f0_);                                        \
    pf1v = __builtin_bit_cast(short8, f1_);                                        \
  }
#define PV(vreg, pf0v, pf1v)                                                       \
  _Pragma("unroll")                                                                \
  for (int dt = 0; dt < 4; ++dt) {                                                 \
    oacc[dt] = __builtin_amdgcn_mfma_f32_32x32x16_bf16(pf0v, vreg[dt],     oacc[dt], 0, 0, 0); \
    oacc[dt] = __builtin_amdgcn_mfma_f32_32x32x16_bf16(pf1v, vreg[4 + dt], oacc[dt], 0, 0, 0); \
  }

  short8 kA[8], kB[8];
  LOAD_K(kA, 0)

  // unroll-2: static kA/kB ping-pong (rule #20), K prefetched one tile ahead,
  // V issued at iter top (consumed after softmax, ~400cy lead over L2 latency)
  for (int t = 0; t < NTH; t += 2) {
    {
      short8 vr[8];
      LOAD_V(vr, t)
      LOAD_K(kB, t + 1)
      f32x16 sacc = zf16;
      QK(kA, sacc)
      short8 pf0, pf1;
      SOFTMAX(sacc, pf0, pf1)
      PV(vr, pf0, pf1)
    }
    {
      short8 vr[8];
      LOAD_V(vr, t + 1)
      if (t + 2 < NTH) LOAD_K(kA, t + 2)
      f32x16 sacc = zf16;
      QK(kB, sacc)
      short8 pf0, pf1;
      SOFTMAX(sacc, pf0, pf1)
      PV(vr, pf0, pf1)
    }
  }
#undef LOAD_K
#undef LOAD_V
#undef QK
#undef SOFTMAX
#undef PV

  // ---- combine halves: lane l32 holds full key-half row sum for qrow = l32 ----
  lsum += __shfl_xor(lsum, 32);

  // ---- split-K merge (only synchronization in the kernel) ----
  __syncthreads();
  float* mo  = smem;                    // 32 x 128
  float* ml1 = smem + 4096;
  float* ml0 = smem + 4128;
  if (g == 1) {
#pragma unroll
    for (int reg = 0; reg < 16; ++reg) {
      int row = (reg & 3) + 8 * (reg >> 2) + 4 * half;
#pragma unroll
      for (int dt = 0; dt < 4; ++dt)
        mo[row * 128 + dt * 32 + l32] = oacc[dt][reg];
    }
    if (half == 0) ml1[l32] = lsum;
  } else {
    if (half == 0) ml0[l32] = lsum;
  }
  __syncthreads();
  if (g == 0) {
    float* Ob = O + (size_t)b * S_LEN * D_DIM;
#pragma unroll
    for (int reg = 0; reg < 16; ++reg) {
      int row = (reg & 3) + 8 * (reg >> 2) + 4 * half;
      float linv = 1.f / (ml0[row] + ml1[row]);
#pragma unroll
      for (int dt = 0; dt < 4; ++dt)
        Ob[(size_t)(qbase + row) * D_DIM + dt * 32 + l32] =
            (oacc[dt][reg] + mo[row * 128 + dt * 32 + l32]) * linv;
    }
  }
}

extern "C" void kernel_launch(void* const* d_in, const int* in_sizes, int n_in,
                              void* d_out, int out_size, void* d_ws, size_t ws_size,
                              hipStream_t stream) {
  const float* Q = (const float*)d_in[0];
  const float* K = (const float*)d_in[1];
  const float* V = (const float*)d_in[2];
  float* O = (float*)d_out;
  unsigned short* Kf = (unsigned short*)d_ws;                       // 8.4 MB frag-major
  unsigned short* Vf = Kf + (size_t)B_N * S_LEN * D_DIM;            // 8.4 MB frag-major
  prep_kernel<<<dim3(1024), dim3(256), 0, stream>>>(K, V, Kf, Vf);
  attn_kernel<<<dim3(1024), dim3(128), 0, stream>>>(Q, Kf, Vf, O);
}